// Round 12
// baseline (38.721 us; speedup 1.0000x reference)
//
#include <hip/hip_runtime.h>

#define N 512
#define D 128
// 1000 * log2(e): sigmoid(x/K) = 1/(1+exp(-x*1000)) = 1/(1+exp2(-x*SCALE))
#define RS_SCALE 1442.6950408889634f
// bucket width == far-threshold 18 (sigmoid saturated to 0/1 within 2^-18)
#define W_INV (1.0f / 18.0f)
#define B_OFF 1530.0f
#define PADV -1600.0f   // pad sorts below all real rs (>= -1442.7), bucket 0
#define NB 172

static __device__ __forceinline__ float rcp_fast(float x) {
    return __builtin_amdgcn_rcpf(x);
}
static __device__ __forceinline__ float exp2_fast(float x) {
    return __builtin_amdgcn_exp2f(x);
}

// Single fused kernel: 512 blocks (1 per row) x 512 threads (8 waves).
// Phase 1: COALESCED cooperative sim row: 16 half-waves x 32 lanes; each
//   half-wave reads one full row per instruction (512 B consecutive) and
//   shfl-reduces dot & ss (offsets <32 stay within the half-wave).
// Phase 2: counting sort (1 elem/thread). Phase 3: windowed sigmoid AP
//   (1 sorted position/thread, wave-uniform bounds, broadcast LDS reads).
// Finalize: mod-512 ticket (poison-proof, wrap-safe).
__global__ __launch_bounds__(512) void map_all_kernel(
    const float* __restrict__ x, const int* __restrict__ tgt,
    float2* __restrict__ av, unsigned* __restrict__ ticket,
    float* __restrict__ out)
{
    const int i = blockIdx.x, t = threadIdx.x;
    const int lane = t & 63;
    __shared__ __align__(16) float xi[D];
    __shared__ float sd[N];     // raw dot(x_row, x_i)
    __shared__ float sss[N];    // ||x_row||^2
    __shared__ int hist[256];   // packed (count<<10)|gtcount -> inclusive scan
    __shared__ int offs[NB];
    __shared__ int wtot[4];
    __shared__ unsigned gbits[16];            // gt bitmask by sorted position
    __shared__ __align__(16) float skey[N];   // bucket-sorted keys
    __shared__ float red[16];
    __shared__ int amLast;

    // ---- phase 0: stage row i; zero LDS tables ----
    if (t < D) xi[t] = x[i * D + t];
    if (t < 256) hist[t] = 0;
    if (t < NB) offs[t] = 0;
    if (t < 16) gbits[t] = 0u;
    __syncthreads();

    // ---- phase 1: cooperative coalesced dots ----
    const int g = t >> 5;    // half-wave id [0,16): owns rows [g*32, g*32+32)
    const int sl = t & 31;   // sub-lane
    const float4 u = ((const float4*)xi)[sl];  // loop-invariant fragment
#pragma unroll 4
    for (int r = 0; r < 32; ++r) {
        const int row = g * 32 + r;
        float4 v = *(const float4*)(x + row * D + sl * 4);  // coalesced 512B
        float dot = v.x * u.x + v.y * u.y + v.z * u.z + v.w * u.w;
        float ss = v.x * v.x + v.y * v.y + v.z * v.z + v.w * v.w;
#pragma unroll
        for (int off = 16; off; off >>= 1) {  // stays within 32-lane half
            dot += __shfl_xor(dot, off);
            ss += __shfl_xor(ss, off);
        }
        if (sl == 0) { sd[row] = dot; sss[row] = ss; }
    }
    __syncthreads();

    // ---- phase 2: scale, bucket, histogram, scan, scatter (1 elem/thread) --
    const int ti = tgt[i];
    const bool self = (t == i);
    const float invT = rcp_fast(fmaxf(sqrtf(sss[t]), 1e-8f));
    const float invI = rcp_fast(fmaxf(sqrtf(sss[i]), 1e-8f));
    const float val = self ? PADV : sd[t] * invT * invI * RS_SCALE;
    const int gti = (!self && tgt[t] == ti) ? 1 : 0;
    int q = (int)((val + B_OFF) * W_INV);
    q = max(0, min(NB - 1, q));
    atomicAdd(&hist[q], (1 << 10) | gti);
    __syncthreads();

    // wave-level inclusive scan of hist[0..255] (waves 0-3)
    int v = (t < 256) ? hist[t] : 0;
#pragma unroll
    for (int off = 1; off < 64; off <<= 1) {
        int uu = __shfl_up(v, off);
        if (lane >= off) v += uu;
    }
    if (t < 256 && lane == 63) wtot[t >> 6] = v;
    __syncthreads();
    if (t < 256) {
        int w = t >> 6, add = 0;
        if (w > 0) add += wtot[0];
        if (w > 1) add += wtot[1];
        if (w > 2) add += wtot[2];
        hist[t] = v + add;
    }
    __syncthreads();

    {
        int base = (q > 0) ? (hist[q - 1] >> 10) : 0;
        int pos = base + atomicAdd(&offs[q], 1);
        skey[pos] = val;
        if (gti) atomicOr(&gbits[pos >> 5], 1u << (pos & 31));
    }
    __syncthreads();

    // ---- phase 3: windowed sigmoid AP, position p = t ----
    const int totGt = hist[NB - 1] & 1023;
    const float4* sk4 = (const float4*)skey;

    const float rj = skey[t];
    const float gtj = (float)((gbits[t >> 5] >> (t & 31)) & 1u);
    int qj = (int)((rj + B_OFF) * W_INV);
    qj = max(0, min(NB - 1, qj));
    // wave-uniform bounds (positions consecutive -> qj monotonic in lane)
    const int qlo = __shfl(qj, 0);
    const int qhi = __shfl(qj, 63);
    const int lo = (qlo > 1) ? (hist[qlo - 2] >> 10) : 0;
    const int e1 = min(qhi + 1, NB - 1);
    const int hi = hist[e1] >> 10;

    float dsum = (float)(N - hi);   // buckets >= qhi+2: exactly 1 each
    float gsum = (float)(totGt - (hist[e1] & 1023));

    float d0 = 0.f, d1 = 0.f, d2 = 0.f, d3 = 0.f;
    float g0 = 0.f, g1 = 0.f, g2 = 0.f, g3 = 0.f;
    int k = lo & ~7;                // elems in [k, lo) saturate to 0: exact
    for (; k + 8 <= hi; k += 8) {
        float4 ka = sk4[k >> 2];        // broadcast (wave-uniform address)
        float4 kb = sk4[(k >> 2) + 1];
        unsigned gw = (gbits[k >> 5] >> (k & 31)) & 0xffu;
        float s0 = rcp_fast(1.f + exp2_fast(rj - ka.x));
        float s1 = rcp_fast(1.f + exp2_fast(rj - ka.y));
        float s2 = rcp_fast(1.f + exp2_fast(rj - ka.z));
        float s3 = rcp_fast(1.f + exp2_fast(rj - ka.w));
        float s4 = rcp_fast(1.f + exp2_fast(rj - kb.x));
        float s5 = rcp_fast(1.f + exp2_fast(rj - kb.y));
        float s6 = rcp_fast(1.f + exp2_fast(rj - kb.z));
        float s7 = rcp_fast(1.f + exp2_fast(rj - kb.w));
        d0 += s0 + s4; d1 += s1 + s5; d2 += s2 + s6; d3 += s3 + s7;
        g0 += ((gw      ) & 1u) ? s0 : 0.f;
        g1 += ((gw >> 1u) & 1u) ? s1 : 0.f;
        g2 += ((gw >> 2u) & 1u) ? s2 : 0.f;
        g3 += ((gw >> 3u) & 1u) ? s3 : 0.f;
        g0 += ((gw >> 4u) & 1u) ? s4 : 0.f;
        g1 += ((gw >> 5u) & 1u) ? s5 : 0.f;
        g2 += ((gw >> 6u) & 1u) ? s6 : 0.f;
        g3 += ((gw >> 7u) & 1u) ? s7 : 0.f;
    }
    dsum += (d0 + d1) + (d2 + d3);
    gsum += (g0 + g1) + (g2 + g3);
    for (; k < hi; ++k) {           // scalar tail (<8 iters)
        float s = rcp_fast(1.f + exp2_fast(rj - skey[k]));
        dsum += s;
        gsum += ((gbits[k >> 5] >> (k & 31)) & 1u) ? s : 0.f;
    }

    float apAcc = gtj * gsum * rcp_fast(dsum + 0.5f);  // pad thread: gtj = 0
    float npAcc = gtj;

    // ---- block reduction (8 waves) ----
#pragma unroll
    for (int off = 32; off; off >>= 1) {
        apAcc += __shfl_down(apAcc, off);
        npAcc += __shfl_down(npAcc, off);
    }
    if (lane == 0) { red[(t >> 6) * 2] = apAcc; red[(t >> 6) * 2 + 1] = npAcc; }
    __syncthreads();
    if (t == 0) {
        float A = 0.f, P = 0.f;
#pragma unroll
        for (int kk = 0; kk < 8; ++kk) { A += red[2 * kk]; P += red[2 * kk + 1]; }
        av[i] = make_float2((P > 0.f) ? (A * rcp_fast(P)) : 0.f,
                            (P > 0.f) ? 1.f : 0.f);
        __threadfence();                       // release av[i]
        unsigned old = atomicAdd(ticket, 1u);
        // mod-512 arrival count: exactly one block per call sees 511,
        // regardless of the ticket's initial (poisoned) value
        amLast = ((old & 511u) == 511u) ? 1 : 0;
    }
    __syncthreads();

    if (amLast) {  // last-arriving block (uniform) reduces av[] -> out
        __threadfence();                       // acquire
        float2 p = av[t];
        float a = p.x, vv = p.y;
#pragma unroll
        for (int off = 32; off; off >>= 1) {
            a += __shfl_down(a, off);
            vv += __shfl_down(vv, off);
        }
        if (lane == 0) { red[(t >> 6) * 2] = a; red[(t >> 6) * 2 + 1] = vv; }
        __syncthreads();
        if (t == 0) {
            float A = 0.f, V = 0.f;
#pragma unroll
            for (int kk = 0; kk < 8; ++kk) { A += red[2 * kk]; V += red[2 * kk + 1]; }
            out[0] = 1.0f - A * rcp_fast(V);
        }
    }
}

extern "C" void kernel_launch(void* const* d_in, const int* in_sizes, int n_in,
                              void* d_out, int out_size, void* d_ws, size_t ws_size,
                              hipStream_t stream) {
    const float* x = (const float*)d_in[0];
    const int* tgt = (const int*)d_in[1];
    float* out = (float*)d_out;

    float2* av = (float2*)d_ws;                          // 4 KB
    unsigned* ticket = (unsigned*)((char*)d_ws + 4096);  // 4 B

    map_all_kernel<<<N, 512, 0, stream>>>(x, tgt, av, ticket, out);
}